// Round 1
// baseline (971.284 us; speedup 1.0000x reference)
//
#include <hip/hip_runtime.h>

// Problem constants
#define BB    16
#define NN    729
#define DD    1152
#define HH_   16
#define HDIM  72
#define NPAD  736
#define HDPAD 96
#define MTOK  (BB*NN)   // 11664

typedef __attribute__((ext_vector_type(8))) short bf16x8;
typedef __attribute__((ext_vector_type(4))) float f32x4;

__device__ __forceinline__ unsigned short f2bf(float f) {
  unsigned u = __float_as_uint(f);
  u += 0x7fffu + ((u >> 16) & 1u);
  return (unsigned short)(u >> 16);
}
__device__ __forceinline__ float bf2f(unsigned short s) {
  return __uint_as_float(((unsigned)s) << 16);
}

// global -> LDS direct 16B load. Pointer casts go through integers to avoid
// illegal addrspace reinterpret_cast; flat->AS3 is a low-32-bit truncation.
__device__ __forceinline__ void gload_lds16(const void* g, void* l) {
  __builtin_amdgcn_global_load_lds(
      (const __attribute__((address_space(1))) void*)(unsigned long long)g,
      (__attribute__((address_space(3))) void*)(unsigned)(unsigned long long)l,
      16, 0, 0);
}

// ---------------- cast kernels ----------------
__global__ __launch_bounds__(256) void cast_x_kernel(const float* __restrict__ in,
                                                     unsigned short* __restrict__ out, int n4) {
  int i = blockIdx.x * 256 + threadIdx.x;
  for (; i < n4; i += gridDim.x * 256) {
    float4 v = ((const float4*)in)[i];
    uint2 o;
    o.x = (unsigned)f2bf(v.x) | ((unsigned)f2bf(v.y) << 16);
    o.y = (unsigned)f2bf(v.z) | ((unsigned)f2bf(v.w) << 16);
    ((uint2*)out)[i] = o;
  }
}

__global__ __launch_bounds__(256) void cast_w_kernel(const float* __restrict__ wq,
                                                     const float* __restrict__ wk,
                                                     const float* __restrict__ wv,
                                                     const float* __restrict__ wo,
                                                     unsigned short* __restrict__ out) {
  const int per = DD * DD / 4;  // 331776 float4 per matrix
  int i = blockIdx.x * 256 + threadIdx.x;
  for (; i < 4 * per; i += gridDim.x * 256) {
    const int which = i / per, off = i - which * per;
    const float* src = which == 0 ? wq : which == 1 ? wk : which == 2 ? wv : wo;
    float4 v = ((const float4*)src)[off];
    uint2 o;
    o.x = (unsigned)f2bf(v.x) | ((unsigned)f2bf(v.y) << 16);
    o.y = (unsigned)f2bf(v.z) | ((unsigned)f2bf(v.w) << 16);
    ((uint2*)out)[i] = o;
  }
}

// ---------------- GEMM: C = A(bf16 Mx1152) * Bw(bf16 rows=features x 1152)^T ----------------
// MODE 0: QKV projection -> scatter bf16 into padded Q/K/V buffers (+bias)
// MODE 1: output projection -> fp32 out (+bias)
template <int MODE>
__global__ __launch_bounds__(256) void gemm_kernel(
    const unsigned short* __restrict__ A,
    const unsigned short* __restrict__ Bw,
    const float* __restrict__ b0, const float* __restrict__ b1, const float* __restrict__ b2,
    unsigned short* __restrict__ O0, unsigned short* __restrict__ O1, unsigned short* __restrict__ O2,
    float* __restrict__ Of) {
  __shared__ __align__(16) unsigned short As[128 * 64];
  __shared__ __align__(16) unsigned short Bs[128 * 64];
  const int tid = threadIdx.x;
  const int w = tid >> 6, l = tid & 63;
  const int lr = l & 15, lh = l >> 4;
  const int m0 = blockIdx.x * 128;
  const int n0 = blockIdx.y * 128;
  const int wr = (w >> 1) * 64, wc = (w & 1) * 64;

  const f32x4 fz = {0.f, 0.f, 0.f, 0.f};
  f32x4 acc[4][4];
#pragma unroll
  for (int i = 0; i < 4; ++i)
#pragma unroll
    for (int j = 0; j < 4; ++j) acc[i][j] = fz;

  for (int kt = 0; kt < 18; ++kt) {
    const int k0 = kt * 64;
#pragma unroll
    for (int c = 0; c < 4; ++c) {
      const int off = (c * 256 + tid) * 16;
      const int row = off >> 7, kb = off & 127;
      int grow = m0 + row;
      if (grow > MTOK - 1) grow = MTOK - 1;
      gload_lds16((const char*)A + (size_t)grow * 2304 + k0 * 2 + kb, (char*)As + off);
    }
#pragma unroll
    for (int c = 0; c < 4; ++c) {
      const int off = (c * 256 + tid) * 16;
      const int row = off >> 7, kb = off & 127;
      gload_lds16((const char*)Bw + (size_t)(n0 + row) * 2304 + k0 * 2 + kb, (char*)Bs + off);
    }
    __syncthreads();
#pragma unroll
    for (int kk = 0; kk < 64; kk += 32) {
      bf16x8 af[4], bf[4];
#pragma unroll
      for (int mi = 0; mi < 4; ++mi)
        af[mi] = *(const bf16x8*)((const char*)As + ((wr + mi * 16 + lr) * 64 + kk + lh * 8) * 2);
#pragma unroll
      for (int ni = 0; ni < 4; ++ni)
        bf[ni] = *(const bf16x8*)((const char*)Bs + ((wc + ni * 16 + lr) * 64 + kk + lh * 8) * 2);
#pragma unroll
      for (int mi = 0; mi < 4; ++mi)
#pragma unroll
        for (int ni = 0; ni < 4; ++ni)
          acc[mi][ni] = __builtin_amdgcn_mfma_f32_16x16x32_bf16(af[mi], bf[ni], acc[mi][ni], 0, 0, 0);
    }
    __syncthreads();
  }

#pragma unroll
  for (int mi = 0; mi < 4; ++mi)
#pragma unroll
    for (int ni = 0; ni < 4; ++ni) {
      const int col = n0 + wc + ni * 16 + lr;
#pragma unroll
      for (int j = 0; j < 4; ++j) {
        const int row = m0 + wr + mi * 16 + lh * 4 + j;
        if (row < MTOK) {
          float v = acc[mi][ni][j];
          if (MODE == 0) {
            const int which = col / DD;
            const int ec = col - which * DD;
            const float* bias = which == 0 ? b0 : (which == 1 ? b1 : b2);
            v += bias[ec];
            unsigned short* dst = which == 0 ? O0 : (which == 1 ? O1 : O2);
            const int h = ec / HDIM, hd = ec - h * HDIM;
            const int bb = row / NN, n = row - bb * NN;
            dst[(((size_t)bb * HH_ + h) * NPAD + n) * HDPAD + hd] = f2bf(v);
          } else {
            Of[(size_t)row * DD + col] = v + b0[col];
          }
        }
      }
    }
}

// ---------------- attention: one WG per (b*h, 32-query tile) ----------------
__global__ __launch_bounds__(256) void attn_kernel(
    const unsigned short* __restrict__ Qb,
    const unsigned short* __restrict__ Kb,
    const unsigned short* __restrict__ Vb,
    const float* __restrict__ tsize,
    float* __restrict__ attn_out,
    unsigned short* __restrict__ Ab) {
  // LDS layout (bytes):
  // LS 0..2944 | MX 2944 | INV 3072 | S 3200 (+32*748*4=95744) ..98944
  // Qt 98944 (+6144) | Kst 105088 (+4*6144) | Vst 129664 (+4*6400) = 155264
  __shared__ __align__(16) char smem[155264];
  float* LS = (float*)smem;
  float* MX = (float*)(smem + 2944);
  float* INV = (float*)(smem + 3072);
  float* S = (float*)(smem + 3200);  // stride 748 floats (2992 B)
  unsigned short* Qt = (unsigned short*)(smem + 98944);
  unsigned short* Kst = (unsigned short*)(smem + 105088);
  unsigned short* Vst = (unsigned short*)(smem + 129664);
  float* Pw = (float*)(smem + 3200);  // reuse S region after PV

  const int tid = threadIdx.x, w = tid >> 6, l = tid & 63;
  const int lr = l & 15, lh = l >> 4;
  const int bh = blockIdx.x, b = bh >> 4, hh = bh & 15;
  const int q0 = blockIdx.y * 32;

  for (int k = tid; k < NPAD; k += 256)
    LS[k] = (k < NN) ? __logf(tsize[b * NN + k]) : -1e30f;

  {
    const char* src = (const char*)(Qb + ((size_t)bh * NPAD + q0) * HDPAD);
    for (int off = tid * 16; off < 6144; off += 4096)
      *(float4*)((char*)Qt + off) = *(const float4*)(src + off);
  }
  __syncthreads();

  const float scale = 0.11785113019775793f;  // 72^-0.5
  const size_t kvbase = (size_t)bh * NPAD * HDPAD;

  // ---- S = Q K^T * scale + log(size) ----
  for (int kt = w; kt < 23; kt += 4) {
    const int k0 = kt * 32;
    const char* ksrc = (const char*)(Kb + kvbase + (size_t)k0 * HDPAD);
    char* kdst = (char*)(Kst + w * 3072);
#pragma unroll
    for (int c = 0; c < 6; ++c) gload_lds16(ksrc + c * 1024 + l * 16, kdst + c * 1024 + l * 16);
    asm volatile("s_waitcnt vmcnt(0)" ::: "memory");

    const f32x4 fz = {0.f, 0.f, 0.f, 0.f};
    f32x4 acc[2][2];
    acc[0][0] = fz; acc[0][1] = fz; acc[1][0] = fz; acc[1][1] = fz;
#pragma unroll
    for (int ks = 0; ks < 96; ks += 32) {
      bf16x8 af[2], bfr[2];
#pragma unroll
      for (int mi = 0; mi < 2; ++mi)
        af[mi] = *(const bf16x8*)(Qt + (mi * 16 + lr) * HDPAD + ks + lh * 8);
#pragma unroll
      for (int ni = 0; ni < 2; ++ni)
        bfr[ni] = *(const bf16x8*)(Kst + w * 3072 + (ni * 16 + lr) * HDPAD + ks + lh * 8);
#pragma unroll
      for (int mi = 0; mi < 2; ++mi)
#pragma unroll
        for (int ni = 0; ni < 2; ++ni)
          acc[mi][ni] = __builtin_amdgcn_mfma_f32_16x16x32_bf16(af[mi], bfr[ni], acc[mi][ni], 0, 0, 0);
    }
#pragma unroll
    for (int mi = 0; mi < 2; ++mi)
#pragma unroll
      for (int ni = 0; ni < 2; ++ni) {
        const int col = k0 + ni * 16 + lr;
        const float lsv = LS[col];
#pragma unroll
        for (int j = 0; j < 4; ++j) {
          const int row = mi * 16 + lh * 4 + j;
          S[row * 748 + col] = acc[mi][ni][j] * scale + lsv;
        }
      }
  }
  __syncthreads();

  // ---- softmax pass1: per-row max & sum (8 lanes per row) ----
  {
    const int r = tid >> 3, sub = tid & 7;
    const float* Srow = S + r * 748;
    float mx = -1e30f;
    for (int c = sub * 92; c < sub * 92 + 92; ++c) mx = fmaxf(mx, Srow[c]);
#pragma unroll
    for (int o = 1; o < 8; o <<= 1) mx = fmaxf(mx, __shfl_xor(mx, o));
    float sum = 0.f;
    for (int c = sub * 92; c < sub * 92 + 92; ++c) sum += __expf(Srow[c] - mx);
#pragma unroll
    for (int o = 1; o < 8; o <<= 1) sum += __shfl_xor(sum, o);
    if (sub == 0) { MX[r] = mx; INV[r] = 1.f / sum; }
  }
  __syncthreads();

  // ---- pass2: P into LDS + coalesced global attn write ----
  {
    const int qv = NN - q0;
    float* ao = attn_out + ((size_t)bh * NN + q0) * NN;
    for (int idx = tid; idx < 32 * NPAD; idx += 256) {
      const int r = idx / NPAD, c = idx - r * NPAD;
      const float p = __expf(S[r * 748 + c] - MX[r]) * INV[r];
      S[r * 748 + c] = p;
      if (c < NN && r < qv) ao[(size_t)r * NN + c] = p;
    }
  }
  __syncthreads();

  // ---- PV ----
  const f32x4 fz = {0.f, 0.f, 0.f, 0.f};
  f32x4 acc2[2][5];
#pragma unroll
  for (int mi = 0; mi < 2; ++mi)
#pragma unroll
    for (int ni = 0; ni < 5; ++ni) acc2[mi][ni] = fz;

  unsigned short* vt = Vst + w * 3200;  // [80][40] bf16, per wave
  if (l < 40) {
#pragma unroll
    for (int r2 = 72; r2 < 80; ++r2) vt[r2 * 40 + l] = 0;
  }

  for (int kt = w; kt < 23; kt += 4) {
    const int k0 = kt * 32;
    {  // stage V^T tile
      const int i = l & 31, half = l >> 5;
      const unsigned short* vsrc = Vb + kvbase + (size_t)(k0 + i) * HDPAD + half * 36;
#pragma unroll
      for (int t = 0; t < 18; ++t) {
        const unsigned vv = *(const unsigned*)(vsrc + t * 2);
        vt[(half * 36 + t * 2) * 40 + i] = (unsigned short)(vv & 0xffffu);
        vt[(half * 36 + t * 2 + 1) * 40 + i] = (unsigned short)(vv >> 16);
      }
    }
    bf16x8 af[2];
#pragma unroll
    for (int mi = 0; mi < 2; ++mi) {
      const float* sp = S + (mi * 16 + lr) * 748 + k0 + lh * 8;
      const float4 f0 = *(const float4*)sp;
      const float4 f1 = *(const float4*)(sp + 4);
      bf16x8 av;
      av[0] = (short)f2bf(f0.x); av[1] = (short)f2bf(f0.y);
      av[2] = (short)f2bf(f0.z); av[3] = (short)f2bf(f0.w);
      av[4] = (short)f2bf(f1.x); av[5] = (short)f2bf(f1.y);
      av[6] = (short)f2bf(f1.z); av[7] = (short)f2bf(f1.w);
      af[mi] = av;
    }
#pragma unroll
    for (int ni = 0; ni < 5; ++ni) {
      const bf16x8 bv = *(const bf16x8*)(vt + (ni * 16 + lr) * 40 + lh * 8);
#pragma unroll
      for (int mi = 0; mi < 2; ++mi)
        acc2[mi][ni] = __builtin_amdgcn_mfma_f32_16x16x32_bf16(af[mi], bv, acc2[mi][ni], 0, 0, 0);
    }
  }
  __syncthreads();  // everyone done reading S

  {
    float* pw = Pw + w * 2560;  // 32x80 per wave
#pragma unroll
    for (int mi = 0; mi < 2; ++mi)
#pragma unroll
      for (int ni = 0; ni < 5; ++ni)
#pragma unroll
        for (int j = 0; j < 4; ++j)
          pw[(mi * 16 + lh * 4 + j) * 80 + ni * 16 + lr] = acc2[mi][ni][j];
  }
  __syncthreads();

  {
    const int qv = NN - q0;
    for (int idx = tid; idx < 32 * HDIM; idx += 256) {
      const int r = idx / HDIM, d = idx - r * HDIM;
      const float s = Pw[r * 80 + d] + Pw[2560 + r * 80 + d] + Pw[5120 + r * 80 + d] + Pw[7680 + r * 80 + d];
      if (r < qv) Ab[((size_t)b * NN + q0 + r) * DD + hh * HDIM + d] = f2bf(s);
    }
  }
}

// ---------------- metric = mean over heads of K ----------------
__global__ __launch_bounds__(256) void metric_kernel(const unsigned short* __restrict__ Kb,
                                                     float* __restrict__ out) {
  const int total = BB * NN * HDIM;
  int idx = blockIdx.x * 256 + threadIdx.x;
  for (; idx < total; idx += gridDim.x * 256) {
    const int b = idx / (NN * HDIM);
    const int rem = idx - b * NN * HDIM;
    const int n = rem / HDIM, d = rem - n * HDIM;
    const unsigned short* kp = Kb + (((size_t)b * HH_) * NPAD + n) * HDPAD + d;
    float s = 0.f;
#pragma unroll
    for (int h = 0; h < HH_; ++h) s += bf2f(kp[(size_t)h * NPAD * HDPAD]);
    out[idx] = s * 0.0625f;
  }
}

extern "C" void kernel_launch(void* const* d_in, const int* in_sizes, int n_in,
                              void* d_out, int out_size, void* d_ws, size_t ws_size,
                              hipStream_t stream) {
  const float* X = (const float*)d_in[0];
  const float* sz = (const float*)d_in[1];
  const float* Wq = (const float*)d_in[2];
  const float* bq = (const float*)d_in[3];
  const float* Wk = (const float*)d_in[4];
  const float* bk = (const float*)d_in[5];
  const float* Wv = (const float*)d_in[6];
  const float* bv = (const float*)d_in[7];
  const float* Wo = (const float*)d_in[8];
  const float* bo = (const float*)d_in[9];

  char* ws = (char*)d_ws;
  unsigned short* Xb = (unsigned short*)ws;                  // 11664x1152 bf16
  unsigned short* Wb = (unsigned short*)(ws + 26873856);     // 4x(1152x1152) bf16 (q,k,v,o)
  unsigned short* Qb = (unsigned short*)(ws + 37490688);     // (16,16,736,96) bf16
  unsigned short* Kb = (unsigned short*)(ws + 73666560);
  unsigned short* Vb = (unsigned short*)(ws + 109842432);
  unsigned short* Ab = (unsigned short*)(ws + 146018304);    // 11664x1152 bf16

  float* out = (float*)d_out;
  float* attn = out + 13436928;
  float* metric = out + 149485824;

  // zero the padded Q/K/V buffers (hd pads + key rows 729..735 must be 0)
  hipMemsetAsync(ws + 37490688, 0, 108527616, stream);

  cast_x_kernel<<<2048, 256, 0, stream>>>(X, Xb, 3359232);
  cast_w_kernel<<<2048, 256, 0, stream>>>(Wq, Wk, Wv, Wo, Wb);

  gemm_kernel<0><<<dim3(92, 27), 256, 0, stream>>>(Xb, Wb, bq, bk, bv, Qb, Kb, Vb, nullptr);

  attn_kernel<<<dim3(256, 23), 256, 0, stream>>>(Qb, Kb, Vb, sz, attn, Ab);

  gemm_kernel<1><<<dim3(92, 9), 256, 0, stream>>>(Ab, Wb + (size_t)3456 * 1152, bo, nullptr, nullptr,
                                                  nullptr, nullptr, nullptr, out);

  metric_kernel<<<2048, 256, 0, stream>>>(Kb, metric);
}

// Round 2
// 773.271 us; speedup vs baseline: 1.2561x; 1.2561x over previous
//
#include <hip/hip_runtime.h>

// Problem constants
#define BB    16
#define NN    729
#define DD    1152
#define HH_   16
#define HDIM  72
#define NPAD  736
#define HDPAD 96
#define MTOK  (BB*NN)   // 11664
#define ESTR  744       // E row stride in bf16 elements

typedef __attribute__((ext_vector_type(8))) short bf16x8;
typedef __attribute__((ext_vector_type(4))) float f32x4;

__device__ __forceinline__ unsigned short f2bf(float f) {
  unsigned u = __float_as_uint(f);
  u += 0x7fffu + ((u >> 16) & 1u);
  return (unsigned short)(u >> 16);
}
__device__ __forceinline__ float bf2f(unsigned short s) {
  return __uint_as_float(((unsigned)s) << 16);
}

__device__ __forceinline__ void gload_lds16(const void* g, void* l) {
  __builtin_amdgcn_global_load_lds(
      (const __attribute__((address_space(1))) void*)(unsigned long long)g,
      (__attribute__((address_space(3))) void*)(unsigned)(unsigned long long)l,
      16, 0, 0);
}

// ---------------- cast kernels ----------------
__global__ __launch_bounds__(256) void cast_x_kernel(const float* __restrict__ in,
                                                     unsigned short* __restrict__ out, int n4) {
  int i = blockIdx.x * 256 + threadIdx.x;
  for (; i < n4; i += gridDim.x * 256) {
    float4 v = ((const float4*)in)[i];
    uint2 o;
    o.x = (unsigned)f2bf(v.x) | ((unsigned)f2bf(v.y) << 16);
    o.y = (unsigned)f2bf(v.z) | ((unsigned)f2bf(v.w) << 16);
    ((uint2*)out)[i] = o;
  }
}

__global__ __launch_bounds__(256) void cast_w_kernel(const float* __restrict__ wq,
                                                     const float* __restrict__ wk,
                                                     const float* __restrict__ wv,
                                                     const float* __restrict__ wo,
                                                     unsigned short* __restrict__ out) {
  const int per = DD * DD / 4;
  int i = blockIdx.x * 256 + threadIdx.x;
  for (; i < 4 * per; i += gridDim.x * 256) {
    const int which = i / per, off = i - which * per;
    const float* src = which == 0 ? wq : which == 1 ? wk : which == 2 ? wv : wo;
    float4 v = ((const float4*)src)[off];
    uint2 o;
    o.x = (unsigned)f2bf(v.x) | ((unsigned)f2bf(v.y) << 16);
    o.y = (unsigned)f2bf(v.z) | ((unsigned)f2bf(v.w) << 16);
    ((uint2*)out)[i] = o;
  }
}

// ---------------- GEMM: C = A(bf16 Mx1152) * Bw(rows=features x 1152)^T ----------------
// MODE 0: QKV projection -> Q/K padded (bh,n,hd) bf16; V transposed (bh,hd,n) bf16
// MODE 1: output projection -> fp32 out (+bias)
template <int MODE>
__global__ __launch_bounds__(256) void gemm_kernel(
    const unsigned short* __restrict__ A,
    const unsigned short* __restrict__ Bw,
    const float* __restrict__ b0, const float* __restrict__ b1, const float* __restrict__ b2,
    unsigned short* __restrict__ O0, unsigned short* __restrict__ O1, unsigned short* __restrict__ O2,
    float* __restrict__ Of) {
  __shared__ __align__(16) unsigned short As[128 * 64];
  __shared__ __align__(16) unsigned short Bs[128 * 64];
  const int tid = threadIdx.x;
  const int w = tid >> 6, l = tid & 63;
  const int lr = l & 15, lh = l >> 4;
  const int m0 = blockIdx.x * 128;
  const int n0 = blockIdx.y * 128;
  const int wr = (w >> 1) * 64, wc = (w & 1) * 64;

  const f32x4 fz = {0.f, 0.f, 0.f, 0.f};
  f32x4 acc[4][4];
#pragma unroll
  for (int i = 0; i < 4; ++i)
#pragma unroll
    for (int j = 0; j < 4; ++j) acc[i][j] = fz;

  for (int kt = 0; kt < 18; ++kt) {
    const int k0 = kt * 64;
#pragma unroll
    for (int c = 0; c < 4; ++c) {
      const int off = (c * 256 + tid) * 16;
      const int row = off >> 7, kb = off & 127;
      int grow = m0 + row;
      if (grow > MTOK - 1) grow = MTOK - 1;
      gload_lds16((const char*)A + (size_t)grow * 2304 + k0 * 2 + kb, (char*)As + off);
    }
#pragma unroll
    for (int c = 0; c < 4; ++c) {
      const int off = (c * 256 + tid) * 16;
      const int row = off >> 7, kb = off & 127;
      gload_lds16((const char*)Bw + (size_t)(n0 + row) * 2304 + k0 * 2 + kb, (char*)Bs + off);
    }
    __syncthreads();
#pragma unroll
    for (int kk = 0; kk < 64; kk += 32) {
      bf16x8 af[4], bf[4];
#pragma unroll
      for (int mi = 0; mi < 4; ++mi)
        af[mi] = *(const bf16x8*)((const char*)As + ((wr + mi * 16 + lr) * 64 + kk + lh * 8) * 2);
#pragma unroll
      for (int ni = 0; ni < 4; ++ni)
        bf[ni] = *(const bf16x8*)((const char*)Bs + ((wc + ni * 16 + lr) * 64 + kk + lh * 8) * 2);
#pragma unroll
      for (int mi = 0; mi < 4; ++mi)
#pragma unroll
        for (int ni = 0; ni < 4; ++ni)
          acc[mi][ni] = __builtin_amdgcn_mfma_f32_16x16x32_bf16(af[mi], bf[ni], acc[mi][ni], 0, 0, 0);
    }
    __syncthreads();
  }

#pragma unroll
  for (int mi = 0; mi < 4; ++mi)
#pragma unroll
    for (int ni = 0; ni < 4; ++ni) {
      const int col = n0 + wc + ni * 16 + lr;
#pragma unroll
      for (int j = 0; j < 4; ++j) {
        const int row = m0 + wr + mi * 16 + lh * 4 + j;
        if (row < MTOK) {
          float v = acc[mi][ni][j];
          if (MODE == 0) {
            const int which = col / DD;
            const int ec = col - which * DD;
            const float* bias = which == 0 ? b0 : (which == 1 ? b1 : b2);
            v += bias[ec];
            const int h = ec / HDIM, hd = ec - h * HDIM;
            const int bb = row / NN, n = row - bb * NN;
            const unsigned short bv = f2bf(v);
            if (which == 0)
              O0[(((size_t)bb * HH_ + h) * NPAD + n) * HDPAD + hd] = bv;
            else if (which == 1)
              O1[(((size_t)bb * HH_ + h) * NPAD + n) * HDPAD + hd] = bv;
            else
              O2[(((size_t)bb * HH_ + h) * HDPAD + hd) * NPAD + n] = bv;  // V transposed
          } else {
            Of[(size_t)row * DD + col] = v + b0[col];
          }
        }
      }
    }
}

// ---------------- attention v2: one WG (512 thr, 8 waves) per (b*h, 64-query tile) ----------------
// E = exp(S) unnormalized, bf16 in LDS. K and V^T B-fragments read directly from global.
__global__ __launch_bounds__(512, 2) void attn_kernel(
    const unsigned short* __restrict__ Qb,
    const unsigned short* __restrict__ Kb,
    const unsigned short* __restrict__ Vt,
    const float* __restrict__ tsize,
    float* __restrict__ attn_out,
    unsigned short* __restrict__ Ab) {
  // LDS: E 95232 | LS 2944 | INV 256 | Qs 12288 = 110720 bytes. red reuses E.
  __shared__ __align__(16) char smem[110720];
  unsigned short* Elds = (unsigned short*)smem;
  float* LS = (float*)(smem + 95232);
  float* INV = (float*)(smem + 98176);
  unsigned short* Qs = (unsigned short*)(smem + 98432);
  float* red = (float*)smem;

  const int tid = threadIdx.x, w = tid >> 6, l = tid & 63;
  const int lr = l & 15, lh = l >> 4;

  // XCD-chunked swizzle: 3072 WGs = 8 XCD chunks x 384
  const int id = blockIdx.x;
  const int nid = (id & 7) * 384 + (id >> 3);
  const int bh = nid / 12, qt = nid - bh * 12;
  const int b = bh >> 4, hh = bh & 15;
  const int q0 = qt * 64;

  for (int k = tid; k < NPAD; k += 512)
    LS[k] = (k < NN) ? __logf(tsize[b * NN + k]) : -1e30f;

  // stage Q tile (64 x 96 bf16), clamp rows past 735
  for (int i = tid; i < 768; i += 512) {
    const int row = i / 12, cw = i - row * 12;
    int grow = q0 + row;
    if (grow > NPAD - 1) grow = NPAD - 1;
    *(float4*)((char*)Qs + row * 192 + cw * 16) =
        *(const float4*)((const char*)Qb + ((size_t)bh * NPAD + grow) * 192 + cw * 16);
  }
  __syncthreads();

  const float scale = 0.11785113019775793f;  // 72^-0.5
  const size_t kbase = (size_t)bh * NPAD * HDPAD;

  // ---- phase 1: E = exp(Q K^T * scale + LS), per-wave k-tiles ----
  for (int kt = w; kt < 23; kt += 8) {
    const int k0 = kt * 32;
    const f32x4 fz = {0.f, 0.f, 0.f, 0.f};
    f32x4 acc[4][2];
#pragma unroll
    for (int mi = 0; mi < 4; ++mi) { acc[mi][0] = fz; acc[mi][1] = fz; }
    const unsigned short* kp = Kb + kbase + (size_t)k0 * HDPAD;
#pragma unroll
    for (int ks = 0; ks < 3; ++ks) {
      const bf16x8 bk0 = *(const bf16x8*)(kp + (size_t)lr * HDPAD + ks * 32 + lh * 8);
      const bf16x8 bk1 = *(const bf16x8*)(kp + (size_t)(16 + lr) * HDPAD + ks * 32 + lh * 8);
#pragma unroll
      for (int mi = 0; mi < 4; ++mi) {
        const bf16x8 aq = *(const bf16x8*)(Qs + (mi * 16 + lr) * HDPAD + ks * 32 + lh * 8);
        acc[mi][0] = __builtin_amdgcn_mfma_f32_16x16x32_bf16(aq, bk0, acc[mi][0], 0, 0, 0);
        acc[mi][1] = __builtin_amdgcn_mfma_f32_16x16x32_bf16(aq, bk1, acc[mi][1], 0, 0, 0);
      }
    }
#pragma unroll
    for (int ni = 0; ni < 2; ++ni) {
      const int col = k0 + ni * 16 + lr;
      const float lsv = LS[col];
#pragma unroll
      for (int mi = 0; mi < 4; ++mi)
#pragma unroll
        for (int j = 0; j < 4; ++j) {
          const int row = mi * 16 + lh * 4 + j;
          Elds[row * ESTR + col] = f2bf(__expf(acc[mi][ni][j] * scale + lsv));
        }
    }
  }
  __syncthreads();

  // ---- phase 2: row sums -> INV (8 threads per row) ----
  {
    const int r = tid >> 3, sub = tid & 7;
    const unsigned short* er = Elds + r * ESTR + sub * 92;
    float s = 0.f;
#pragma unroll
    for (int i = 0; i < 23; ++i) {
      const uint2 ev = *(const uint2*)(er + i * 4);
      s += bf2f(ev.x & 0xffffu) + bf2f(ev.x >> 16) + bf2f(ev.y & 0xffffu) + bf2f(ev.y >> 16);
    }
#pragma unroll
    for (int o = 1; o < 8; o <<= 1) s += __shfl_xor(s, o);
    if (sub == 0) INV[r] = 1.f / s;
  }
  __syncthreads();

  // ---- phase 3: normalized P -> global attn (coalesced stripes) ----
  const int qv = NN - q0;
  {
    const int r = tid >> 3, sub = tid & 7;
    if (r < qv) {
      const float inv = INV[r];
      float* ao = attn_out + ((size_t)bh * NN + (q0 + r)) * NN;
      const unsigned short* er = Elds + r * ESTR;
#pragma unroll
      for (int i = 0; i < 23; ++i) {
        const int col = i * 32 + sub * 4;
        if (col + 4 <= NN) {
          const uint2 ev = *(const uint2*)(er + col);
          float4 o;
          o.x = bf2f(ev.x & 0xffffu) * inv;
          o.y = bf2f(ev.x >> 16) * inv;
          o.z = bf2f(ev.y & 0xffffu) * inv;
          o.w = bf2f(ev.y >> 16) * inv;
          *(float4*)(ao + col) = o;
        } else if (col < NN) {
          for (int c = col; c < NN; ++c) ao[c] = bf2f(er[c]) * inv;
        }
      }
    }
  }

  // ---- phase 4: PV. wave = (M-tile m, k-half). V^T B-frags direct from global. ----
  const int m = w & 3, khalf = w >> 2;
  const f32x4 fz = {0.f, 0.f, 0.f, 0.f};
  f32x4 acc2[5];
#pragma unroll
  for (int ni = 0; ni < 5; ++ni) acc2[ni] = fz;
  {
    const int kt0 = khalf * 12, kt1 = khalf ? 23 : 12;
    const unsigned short* vp = Vt + (size_t)bh * HDPAD * NPAD;
    for (int kt = kt0; kt < kt1; ++kt) {
      const int k0 = kt * 32;
      const bf16x8 ap = *(const bf16x8*)(Elds + (m * 16 + lr) * ESTR + k0 + lh * 8);
#pragma unroll
      for (int ni = 0; ni < 5; ++ni) {
        const bf16x8 bv = *(const bf16x8*)(vp + (size_t)(ni * 16 + lr) * NPAD + k0 + lh * 8);
        acc2[ni] = __builtin_amdgcn_mfma_f32_16x16x32_bf16(ap, bv, acc2[ni], 0, 0, 0);
      }
    }
  }
  __syncthreads();  // all PV reads of Elds done

  if (w >= 4) {
    float* rd = red + m * 1280;
#pragma unroll
    for (int ni = 0; ni < 5; ++ni)
#pragma unroll
      for (int j = 0; j < 4; ++j)
        rd[(lh * 4 + j) * 80 + ni * 16 + lr] = acc2[ni][j];
  }
  __syncthreads();
  if (w < 4) {
    const float* rd = red + m * 1280;
#pragma unroll
    for (int ni = 0; ni < 5; ++ni) {
      const int d = ni * 16 + lr;
      if (d < HDIM) {
#pragma unroll
        for (int j = 0; j < 4; ++j) {
          const int rrow = m * 16 + lh * 4 + j;
          const int q = q0 + rrow;
          if (q < NN) {
            const float s2 = (acc2[ni][j] + rd[(lh * 4 + j) * 80 + d]) * INV[rrow];
            Ab[((size_t)b * NN + q) * DD + hh * HDIM + d] = f2bf(s2);
          }
        }
      }
    }
  }
}

// ---------------- metric = mean over heads of K ----------------
__global__ __launch_bounds__(256) void metric_kernel(const unsigned short* __restrict__ Kb,
                                                     float* __restrict__ out) {
  const int total = BB * NN * HDIM;
  int idx = blockIdx.x * 256 + threadIdx.x;
  for (; idx < total; idx += gridDim.x * 256) {
    const int b = idx / (NN * HDIM);
    const int rem = idx - b * NN * HDIM;
    const int n = rem / HDIM, d = rem - n * HDIM;
    const unsigned short* kp = Kb + (((size_t)b * HH_) * NPAD + n) * HDPAD + d;
    float s = 0.f;
#pragma unroll
    for (int h = 0; h < HH_; ++h) s += bf2f(kp[(size_t)h * NPAD * HDPAD]);
    out[idx] = s * 0.0625f;
  }
}

extern "C" void kernel_launch(void* const* d_in, const int* in_sizes, int n_in,
                              void* d_out, int out_size, void* d_ws, size_t ws_size,
                              hipStream_t stream) {
  const float* X = (const float*)d_in[0];
  const float* sz = (const float*)d_in[1];
  const float* Wq = (const float*)d_in[2];
  const float* bq = (const float*)d_in[3];
  const float* Wk = (const float*)d_in[4];
  const float* bk = (const float*)d_in[5];
  const float* Wv = (const float*)d_in[6];
  const float* bv = (const float*)d_in[7];
  const float* Wo = (const float*)d_in[8];
  const float* bo = (const float*)d_in[9];

  char* ws = (char*)d_ws;
  unsigned short* Xb = (unsigned short*)ws;                  // 11664x1152 bf16
  unsigned short* Wb = (unsigned short*)(ws + 26873856);     // 4x(1152x1152) bf16 (q,k,v,o)
  unsigned short* Qb = (unsigned short*)(ws + 37490688);     // (16,16,736,96) bf16
  unsigned short* Kb = (unsigned short*)(ws + 73666560);     // (16,16,736,96) bf16
  unsigned short* Vt = (unsigned short*)(ws + 109842432);    // (16,16,96,736) bf16 transposed
  unsigned short* Ab = (unsigned short*)(ws + 146018304);    // 11664x1152 bf16

  float* out = (float*)d_out;
  float* attn = out + 13436928;
  float* metric = out + 149485824;

  // zero padded Q/K/Vt buffers (pads must be 0)
  hipMemsetAsync(ws + 37490688, 0, 108527616, stream);

  cast_x_kernel<<<2048, 256, 0, stream>>>(X, Xb, 3359232);
  cast_w_kernel<<<2048, 256, 0, stream>>>(Wq, Wk, Wv, Wo, Wb);

  gemm_kernel<0><<<dim3(92, 27), 256, 0, stream>>>(Xb, Wb, bq, bk, bv, Qb, Kb, Vt, nullptr);

  attn_kernel<<<3072, 512, 0, stream>>>(Qb, Kb, Vt, sz, attn, Ab);

  gemm_kernel<1><<<dim3(92, 9), 256, 0, stream>>>(Ab, Wb + (size_t)3456 * 1152, bo, nullptr, nullptr,
                                                  nullptr, nullptr, nullptr, out);

  metric_kernel<<<2048, 256, 0, stream>>>(Kb, metric);
}

// Round 3
// 670.210 us; speedup vs baseline: 1.4492x; 1.1538x over previous
//
#include <hip/hip_runtime.h>

// Problem constants
#define BB    16
#define NN    729
#define DD    1152
#define HH_   16
#define HDIM  72
#define NPAD  736
#define HDPAD 96
#define MTOK  (BB*NN)   // 11664
#define ESTR  768       // E row stride in bf16 elements (bank-aligned, XOR-swizzled)

typedef __attribute__((ext_vector_type(8))) short bf16x8;
typedef __attribute__((ext_vector_type(4))) float f32x4;

__device__ __forceinline__ unsigned short f2bf(float f) {
  unsigned u = __float_as_uint(f);
  u += 0x7fffu + ((u >> 16) & 1u);
  return (unsigned short)(u >> 16);
}
__device__ __forceinline__ float bf2f(unsigned short s) {
  return __uint_as_float(((unsigned)s) << 16);
}

__device__ __forceinline__ void gload_lds16(const void* g, void* l) {
  __builtin_amdgcn_global_load_lds(
      (const __attribute__((address_space(1))) void*)(unsigned long long)g,
      (__attribute__((address_space(3))) void*)(unsigned)(unsigned long long)l,
      16, 0, 0);
}

// ---------------- cast kernels ----------------
__global__ __launch_bounds__(256) void cast_x_kernel(const float* __restrict__ in,
                                                     unsigned short* __restrict__ out, int n4) {
  int i = blockIdx.x * 256 + threadIdx.x;
  for (; i < n4; i += gridDim.x * 256) {
    float4 v = ((const float4*)in)[i];
    uint2 o;
    o.x = (unsigned)f2bf(v.x) | ((unsigned)f2bf(v.y) << 16);
    o.y = (unsigned)f2bf(v.z) | ((unsigned)f2bf(v.w) << 16);
    ((uint2*)out)[i] = o;
  }
}

__global__ __launch_bounds__(256) void cast_w_kernel(const float* __restrict__ wq,
                                                     const float* __restrict__ wk,
                                                     const float* __restrict__ wv,
                                                     const float* __restrict__ wo,
                                                     unsigned short* __restrict__ out) {
  const int per = DD * DD / 4;
  int i = blockIdx.x * 256 + threadIdx.x;
  for (; i < 4 * per; i += gridDim.x * 256) {
    const int which = i / per, off = i - which * per;
    const float* src = which == 0 ? wq : which == 1 ? wk : which == 2 ? wv : wo;
    float4 v = ((const float4*)src)[off];
    uint2 o;
    o.x = (unsigned)f2bf(v.x) | ((unsigned)f2bf(v.y) << 16);
    o.y = (unsigned)f2bf(v.z) | ((unsigned)f2bf(v.w) << 16);
    ((uint2*)out)[i] = o;
  }
}

// ---------------- log(size) table: (16, 736) fp32 ----------------
__global__ __launch_bounds__(256) void ls_kernel(const float* __restrict__ tsize,
                                                 float* __restrict__ LSg) {
  const int idx = blockIdx.x * 256 + threadIdx.x;
  if (idx < BB * NPAD) {
    const int b = idx / NPAD, k = idx - b * NPAD;
    LSg[idx] = (k < NN) ? __logf(tsize[b * NN + k]) : -1e30f;
  }
}

// ---------------- GEMM: C = A(bf16 Mx1152) * Bw(rows=features x 1152)^T ----------------
template <int MODE>
__global__ __launch_bounds__(256) void gemm_kernel(
    const unsigned short* __restrict__ A,
    const unsigned short* __restrict__ Bw,
    const float* __restrict__ b0, const float* __restrict__ b1, const float* __restrict__ b2,
    unsigned short* __restrict__ O0, unsigned short* __restrict__ O1, unsigned short* __restrict__ O2,
    float* __restrict__ Of) {
  __shared__ __align__(16) unsigned short As[128 * 64];
  __shared__ __align__(16) unsigned short Bs[128 * 64];
  const int tid = threadIdx.x;
  const int w = tid >> 6, l = tid & 63;
  const int lr = l & 15, lh = l >> 4;
  const int m0 = blockIdx.x * 128;
  const int n0 = blockIdx.y * 128;
  const int wr = (w >> 1) * 64, wc = (w & 1) * 64;

  const f32x4 fz = {0.f, 0.f, 0.f, 0.f};
  f32x4 acc[4][4];
#pragma unroll
  for (int i = 0; i < 4; ++i)
#pragma unroll
    for (int j = 0; j < 4; ++j) acc[i][j] = fz;

  for (int kt = 0; kt < 18; ++kt) {
    const int k0 = kt * 64;
#pragma unroll
    for (int c = 0; c < 4; ++c) {
      const int off = (c * 256 + tid) * 16;
      const int row = off >> 7, kb = off & 127;
      int grow = m0 + row;
      if (grow > MTOK - 1) grow = MTOK - 1;
      gload_lds16((const char*)A + (size_t)grow * 2304 + k0 * 2 + kb, (char*)As + off);
    }
#pragma unroll
    for (int c = 0; c < 4; ++c) {
      const int off = (c * 256 + tid) * 16;
      const int row = off >> 7, kb = off & 127;
      gload_lds16((const char*)Bw + (size_t)(n0 + row) * 2304 + k0 * 2 + kb, (char*)Bs + off);
    }
    __syncthreads();
#pragma unroll
    for (int kk = 0; kk < 64; kk += 32) {
      bf16x8 af[4], bf[4];
#pragma unroll
      for (int mi = 0; mi < 4; ++mi)
        af[mi] = *(const bf16x8*)((const char*)As + ((wr + mi * 16 + lr) * 64 + kk + lh * 8) * 2);
#pragma unroll
      for (int ni = 0; ni < 4; ++ni)
        bf[ni] = *(const bf16x8*)((const char*)Bs + ((wc + ni * 16 + lr) * 64 + kk + lh * 8) * 2);
#pragma unroll
      for (int mi = 0; mi < 4; ++mi)
#pragma unroll
        for (int ni = 0; ni < 4; ++ni)
          acc[mi][ni] = __builtin_amdgcn_mfma_f32_16x16x32_bf16(af[mi], bf[ni], acc[mi][ni], 0, 0, 0);
    }
    __syncthreads();
  }

#pragma unroll
  for (int mi = 0; mi < 4; ++mi)
#pragma unroll
    for (int ni = 0; ni < 4; ++ni) {
      const int col = n0 + wc + ni * 16 + lr;
#pragma unroll
      for (int j = 0; j < 4; ++j) {
        const int row = m0 + wr + mi * 16 + lh * 4 + j;
        if (row < MTOK) {
          float v = acc[mi][ni][j];
          if (MODE == 0) {
            const int which = col / DD;
            const int ec = col - which * DD;
            const float* bias = which == 0 ? b0 : (which == 1 ? b1 : b2);
            v += bias[ec];
            const int h = ec / HDIM, hd = ec - h * HDIM;
            const int bb = row / NN, n = row - bb * NN;
            const unsigned short bv = f2bf(v);
            if (which == 0)
              O0[(((size_t)bb * HH_ + h) * NPAD + n) * HDPAD + hd] = bv;
            else if (which == 1)
              O1[(((size_t)bb * HH_ + h) * NPAD + n) * HDPAD + hd] = bv;
            else
              O2[(((size_t)bb * HH_ + h) * HDPAD + hd) * NPAD + n] = bv;  // V transposed
          } else {
            Of[(size_t)row * DD + col] = v + b0[col];
          }
        }
      }
    }
}

// ---------------- attention v3: one WG (512 thr, 8 waves) per (b*h, 32-query tile) ----------------
// E = exp(S) unnormalized bf16, XOR-swizzled in LDS. Q/K/V^T fragments direct from global.
// LDS ~49 KB -> 3 WGs/CU; __launch_bounds__(512,6) targets <=85 VGPR -> 24 waves/CU.
__global__ __launch_bounds__(512, 6) void attn_kernel(
    const unsigned short* __restrict__ Qb,
    const unsigned short* __restrict__ Kb,
    const unsigned short* __restrict__ Vt,
    const float* __restrict__ LSg,
    float* __restrict__ attn_out,
    unsigned short* __restrict__ Ab) {
  // LDS: E 32x768 bf16 = 49152 | INV 128  => 49280 bytes. red reuses E after PV.
  __shared__ __align__(16) char smem[49280];
  unsigned short* Elds = (unsigned short*)smem;
  float* INV = (float*)(smem + 49152);
  float* red = (float*)smem;

  const int tid = threadIdx.x, w = tid >> 6, l = tid & 63;
  const int lr = l & 15, lh = l >> 4;

  // bijective XCD-chunked swizzle: 5888 WGs = 8 chunks x 736; 32 bh per chunk
  const int id = blockIdx.x;
  const int nid = (id & 7) * 736 + (id >> 3);
  const int bh = nid / 23, qt = nid - bh * 23;
  const int b = bh >> 4, hh = bh & 15;
  const int q0 = qt * 32;

  const float scale = 0.11785113019775793f;  // 72^-0.5
  const size_t kvbase = (size_t)bh * NPAD * HDPAD;
  const unsigned short* qp = Qb + kvbase + (size_t)q0 * HDPAD;

  // ---- phase 1: E = exp(Q K^T * scale + LS); per-wave k-tiles, frags from global ----
  for (int kt = w; kt < 23; kt += 8) {
    const int k0 = kt * 32;
    const f32x4 fz = {0.f, 0.f, 0.f, 0.f};
    f32x4 acc[2][2];
    acc[0][0] = fz; acc[0][1] = fz; acc[1][0] = fz; acc[1][1] = fz;
    const unsigned short* kp = Kb + kvbase + (size_t)k0 * HDPAD;
#pragma unroll
    for (int ks = 0; ks < 3; ++ks) {
      const bf16x8 bk0 = *(const bf16x8*)(kp + (size_t)lr * HDPAD + ks * 32 + lh * 8);
      const bf16x8 bk1 = *(const bf16x8*)(kp + (size_t)(16 + lr) * HDPAD + ks * 32 + lh * 8);
#pragma unroll
      for (int mi = 0; mi < 2; ++mi) {
        const bf16x8 aq = *(const bf16x8*)(qp + (size_t)(mi * 16 + lr) * HDPAD + ks * 32 + lh * 8);
        acc[mi][0] = __builtin_amdgcn_mfma_f32_16x16x32_bf16(aq, bk0, acc[mi][0], 0, 0, 0);
        acc[mi][1] = __builtin_amdgcn_mfma_f32_16x16x32_bf16(aq, bk1, acc[mi][1], 0, 0, 0);
      }
    }
#pragma unroll
    for (int ni = 0; ni < 2; ++ni) {
      const int col = k0 + ni * 16 + lr;
      const float lsv = LSg[b * NPAD + col];
#pragma unroll
      for (int mi = 0; mi < 2; ++mi)
#pragma unroll
        for (int j = 0; j < 4; ++j) {
          const int row = mi * 16 + lh * 4 + j;
          const int swcol = col ^ ((row & 7) << 3);
          Elds[row * ESTR + swcol] = f2bf(__expf(acc[mi][ni][j] * scale + lsv));
        }
    }
  }
  __syncthreads();

  // ---- phase 2: row sums -> INV (16 threads per row) ----
  {
    const int r = tid >> 4, sub = tid & 15;
    const unsigned short* er = Elds + r * ESTR;
    const int sw = (r & 7) << 3;
    float s = 0.f;
#pragma unroll
    for (int i = 0; i < 12; ++i) {
      const int col = i * 64 + sub * 4;
      if (col < NPAD) {
        const uint2 ev = *(const uint2*)(er + (col ^ sw));
        s += bf2f(ev.x & 0xffffu) + bf2f(ev.x >> 16) + bf2f(ev.y & 0xffffu) + bf2f(ev.y >> 16);
      }
    }
#pragma unroll
    for (int o = 1; o < 16; o <<= 1) s += __shfl_xor(s, o);
    if (sub == 0) INV[r] = 1.f / s;
  }
  __syncthreads();

  // ---- phase 3: normalized P -> global attn (coalesced) ----
  const int qv = NN - q0;
  {
    const int r = tid >> 4, sub = tid & 15;
    if (r < qv) {
      const float inv = INV[r];
      float* ao = attn_out + ((size_t)bh * NN + (q0 + r)) * NN;
      const unsigned short* er = Elds + r * ESTR;
      const int sw = (r & 7) << 3;
#pragma unroll
      for (int i = 0; i < 12; ++i) {
        const int col = i * 64 + sub * 4;
        if (col + 4 <= NN) {
          const uint2 ev = *(const uint2*)(er + (col ^ sw));
          float4 o;
          o.x = bf2f(ev.x & 0xffffu) * inv;
          o.y = bf2f(ev.x >> 16) * inv;
          o.z = bf2f(ev.y & 0xffffu) * inv;
          o.w = bf2f(ev.y >> 16) * inv;
          *(float4*)(ao + col) = o;
        } else if (col < NN) {
          for (int c = col; c < NN; ++c) ao[c] = bf2f(er[c ^ sw]) * inv;
        }
      }
    }
  }

  // ---- phase 4: PV. wave = (m half, k quarter). V^T B-frags direct from global. ----
  const int m = w & 1, kq = w >> 1;
  const f32x4 fz = {0.f, 0.f, 0.f, 0.f};
  f32x4 acc2[5];
#pragma unroll
  for (int ni = 0; ni < 5; ++ni) acc2[ni] = fz;
  {
    const int kt0 = kq * 6, kt1 = (kq == 3) ? 23 : kt0 + 6;
    const unsigned short* vp = Vt + (size_t)bh * HDPAD * NPAD;
    const int row = m * 16 + lr;
    const int sw = (row & 7) << 3;
    for (int kt = kt0; kt < kt1; ++kt) {
      const int k0 = kt * 32;
      const bf16x8 ap = *(const bf16x8*)(Elds + row * ESTR + ((k0 + lh * 8) ^ sw));
#pragma unroll
      for (int ni = 0; ni < 5; ++ni) {
        const bf16x8 bv = *(const bf16x8*)(vp + (size_t)(ni * 16 + lr) * NPAD + k0 + lh * 8);
        acc2[ni] = __builtin_amdgcn_mfma_f32_16x16x32_bf16(ap, bv, acc2[ni], 0, 0, 0);
      }
    }
  }
  __syncthreads();  // all PV reads of Elds done

  if (kq > 0) {
    float* rd = red + ((kq - 1) * 2 + m) * 1344;  // 16 x 84 fp32
#pragma unroll
    for (int ni = 0; ni < 5; ++ni)
#pragma unroll
      for (int j = 0; j < 4; ++j)
        rd[(lh * 4 + j) * 84 + ni * 16 + lr] = acc2[ni][j];
  }
  __syncthreads();
  if (kq == 0) {
#pragma unroll
    for (int ni = 0; ni < 5; ++ni) {
      const int d = ni * 16 + lr;
      if (d < HDIM) {
#pragma unroll
        for (int j = 0; j < 4; ++j) {
          const int rrow = m * 16 + lh * 4 + j;
          const int q = q0 + rrow;
          if (q < NN) {
            const int ro = (lh * 4 + j) * 84 + ni * 16 + lr;
            const float s2 = acc2[ni][j] + red[m * 1344 + ro] + red[(2 + m) * 1344 + ro] +
                             red[(4 + m) * 1344 + ro];
            Ab[((size_t)b * NN + q) * DD + hh * HDIM + d] = f2bf(s2 * INV[rrow]);
          }
        }
      }
    }
  }
}

// ---------------- metric = mean over heads of K ----------------
__global__ __launch_bounds__(256) void metric_kernel(const unsigned short* __restrict__ Kb,
                                                     float* __restrict__ out) {
  const int total = BB * NN * HDIM;
  int idx = blockIdx.x * 256 + threadIdx.x;
  for (; idx < total; idx += gridDim.x * 256) {
    const int b = idx / (NN * HDIM);
    const int rem = idx - b * NN * HDIM;
    const int n = rem / HDIM, d = rem - n * HDIM;
    const unsigned short* kp = Kb + (((size_t)b * HH_) * NPAD + n) * HDPAD + d;
    float s = 0.f;
#pragma unroll
    for (int h = 0; h < HH_; ++h) s += bf2f(kp[(size_t)h * NPAD * HDPAD]);
    out[idx] = s * 0.0625f;
  }
}

extern "C" void kernel_launch(void* const* d_in, const int* in_sizes, int n_in,
                              void* d_out, int out_size, void* d_ws, size_t ws_size,
                              hipStream_t stream) {
  const float* X = (const float*)d_in[0];
  const float* sz = (const float*)d_in[1];
  const float* Wq = (const float*)d_in[2];
  const float* bq = (const float*)d_in[3];
  const float* Wk = (const float*)d_in[4];
  const float* bk = (const float*)d_in[5];
  const float* Wv = (const float*)d_in[6];
  const float* bv = (const float*)d_in[7];
  const float* Wo = (const float*)d_in[8];
  const float* bo = (const float*)d_in[9];

  char* ws = (char*)d_ws;
  unsigned short* Xb = (unsigned short*)ws;                  // 11664x1152 bf16
  unsigned short* Wb = (unsigned short*)(ws + 26873856);     // 4x(1152x1152) bf16 (q,k,v,o)
  unsigned short* Qb = (unsigned short*)(ws + 37490688);     // (16,16,736,96) bf16
  unsigned short* Kb = (unsigned short*)(ws + 73666560);     // (16,16,736,96) bf16
  unsigned short* Vt = (unsigned short*)(ws + 109842432);    // (16,16,96,736) bf16 transposed
  unsigned short* Ab = (unsigned short*)(ws + 146018304);    // 11664x1152 bf16
  float* LSg = (float*)ws;  // (16,736) fp32 log-size table; aliases Xb, written AFTER gemm<0>

  float* out = (float*)d_out;
  float* attn = out + 13436928;
  float* metric = out + 149485824;

  // zero padded Q/K/Vt buffers (pads must be 0)
  hipMemsetAsync(ws + 37490688, 0, 108527616, stream);

  cast_x_kernel<<<2048, 256, 0, stream>>>(X, Xb, 3359232);
  cast_w_kernel<<<2048, 256, 0, stream>>>(Wq, Wk, Wv, Wo, Wb);

  gemm_kernel<0><<<dim3(92, 27), 256, 0, stream>>>(Xb, Wb, bq, bk, bv, Qb, Kb, Vt, nullptr);

  // log(size) table (aliases Xb region; Xb is dead after gemm<0>)
  ls_kernel<<<46, 256, 0, stream>>>(sz, LSg);

  attn_kernel<<<5888, 512, 0, stream>>>(Qb, Kb, Vt, LSg, attn, Ab);

  gemm_kernel<1><<<dim3(92, 9), 256, 0, stream>>>(Ab, Wb + (size_t)3456 * 1152, bo, nullptr, nullptr,
                                                  nullptr, nullptr, nullptr, out);

  metric_kernel<<<2048, 256, 0, stream>>>(Kb, metric);
}